// Round 5
// baseline (2991.494 us; speedup 1.0000x reference)
//
#include <hip/hip_runtime.h>

// GGCNConv: N=50000 nodes, E=1600000 edges (64 | E), D=64
// ws layout (floats): g0[N*64] g1[N*64] srcL[N*64] dstL[N*64] agg[N*64] stats[512]
// d_out: node_out[N*64] then edge_out[E*64]; m staged in edge_out region.

typedef float f4 __attribute__((ext_vector_type(4)));   // native vec4 for NT builtins
typedef float f2 __attribute__((ext_vector_type(2)));

// Native (non-CAS) float atomic add, packed where the target supports it.
__device__ __forceinline__ void atomic_add2(float* p, float a, float b) {
#if __has_builtin(__builtin_amdgcn_flat_atomic_fadd_v2f32)
    f2 v = {a, b};
    (void)__builtin_amdgcn_flat_atomic_fadd_v2f32(reinterpret_cast<f2*>(p), v);
#else
    (void)unsafeAtomicAdd(p, a);        // native global_atomic_add_f32, no CAS loop
    (void)unsafeAtomicAdd(p + 1, b);
#endif
}

__global__ __launch_bounds__(256, 2) void node_kernel(
    const float* __restrict__ x,
    const float* __restrict__ Wg,   // Wg0 = Wg, Wg1 = Wg + 4096
    const float* __restrict__ Ws, const float* __restrict__ bs,
    const float* __restrict__ Wd, const float* __restrict__ bd,
    float* __restrict__ g0, float* __restrict__ g1,
    float* __restrict__ srcL, float* __restrict__ dstL,
    int N, int ntiles)
{
    __shared__ float ldsA[4][4096];
    const int lane = threadIdx.x & 63;
    const int wid  = threadIdx.x >> 6;
    float* lds = ldsA[wid];
    const int nw = gridDim.x * 4;
    const float bsv = bs[lane], bdv = bd[lane];

    for (int tile = blockIdx.x * 4 + wid; tile < ntiles; tile += nw) {
        const int r0 = tile * 64;
        {
            const int rb = lane >> 5, c2 = lane & 31;
            #pragma unroll
            for (int i = 0; i < 32; ++i) {
                int r = 2 * i + rb;
                int row = r0 + r; if (row >= N) row = N - 1;
                float2 v = *reinterpret_cast<const float2*>(x + (size_t)row * 64 + 2 * c2);
                int p = ((c2 + r) & 31) << 1;
                *reinterpret_cast<float2*>(&lds[r * 64 + p]) = v;
            }
        }
        float xr[64];
        #pragma unroll
        for (int kk = 0; kk < 32; ++kk) {
            int p = ((kk + lane) & 31) << 1;
            float2 v = *reinterpret_cast<const float2*>(&lds[lane * 64 + p]);
            xr[2 * kk] = v.x; xr[2 * kk + 1] = v.y;
        }
        #pragma unroll 1
        for (int mt = 0; mt < 4; ++mt) {
            const float* __restrict__ Wm = (mt == 0) ? Wg : (mt == 1) ? (Wg + 4096)
                                         : (mt == 2) ? Ws : Wd;
            #pragma unroll 1
            for (int ct = 0; ct < 2; ++ct) {
                float acc[32];
                #pragma unroll
                for (int c = 0; c < 32; ++c) acc[c] = 0.f;
                const float* __restrict__ Wp = Wm + ct * 32;
                #pragma unroll
                for (int k = 0; k < 64; ++k) {
                    float a = xr[k];
                    #pragma unroll
                    for (int c = 0; c < 32; ++c)
                        acc[c] = fmaf(a, Wp[k * 64 + c], acc[c]);
                }
                #pragma unroll
                for (int cc = 0; cc < 16; ++cc) {
                    int q = ct * 16 + cc;
                    int p = ((q + lane) & 31) << 1;
                    *reinterpret_cast<float2*>(&lds[lane * 64 + p]) =
                        make_float2(acc[2 * cc], acc[2 * cc + 1]);
                }
            }
            float bv = (mt == 2) ? bsv : (mt == 3) ? bdv : 0.f;
            float* __restrict__ op = (mt == 0) ? g0 : (mt == 1) ? g1 : (mt == 2) ? srcL : dstL;
            for (int j = 0; j < 64; ++j) {
                int row = r0 + j;
                if (row >= N) break;
                int p = ((((lane >> 1) + j) & 31) << 1) | (lane & 1);
                op[(size_t)row * 64 + lane] = lds[j * 64 + p] + bv;
            }
        }
    }
}

// Edge kernel, float4 granularity throughout.
// LDS 64x64 tile, qword-rotation swizzle: (row, q4) -> float4 slot row*16 + ((q4+row)&15)
__global__ __launch_bounds__(256, 4) void edge_kernel(
    const float* __restrict__ ea, const int* __restrict__ eidx,
    const float* __restrict__ W2, const float* __restrict__ bg,
    const float* __restrict__ g0, const float* __restrict__ g1,
    const float* __restrict__ dstL, float* __restrict__ m_out,
    float* __restrict__ agg, float* __restrict__ stats,
    int E, int ntiles)
{
    __shared__ float lds[4096];
    const int tid  = threadIdx.x;
    const int lane = tid & 63;
    const int wid  = __builtin_amdgcn_readfirstlane(tid >> 6);  // wave-uniform SGPR
    const int q    = lane & 15;   // column qword 0..15
    const int rg   = lane >> 4;   // edge-within-group 0..3
    const f4 bgv = *reinterpret_cast<const f4*>(bg + q * 4);
    f4 ssum = {0.f, 0.f, 0.f, 0.f};
    f4 ssq  = {0.f, 0.f, 0.f, 0.f};

    for (int tile = blockIdx.x; tile < ntiles; tile += gridDim.x) {
        const long e0 = (long)tile * 64;
        // phase 1: stage ea tile (1024 float4s), NT loads, swizzled b128 writes
        #pragma unroll
        for (int j = 0; j < 4; ++j) {
            int fp = tid + j * 256;           // float4 index 0..1023
            int row = fp >> 4, qc = fp & 15;  // 16 consecutive lanes -> one row
            f4 v = __builtin_nontemporal_load(
                reinterpret_cast<const f4*>(ea + (e0 + row) * 64 + qc * 4));
            int a4 = row * 16 + ((qc + row) & 15);
            *reinterpret_cast<f4*>(&lds[a4 * 4]) = v;
        }
        __syncthreads();
        // phase 2: thread owns edge row `lane`; computes cols [wid*16, wid*16+16)
        float acc[16];
        #pragma unroll
        for (int c = 0; c < 16; ++c) acc[c] = 0.f;
        {
            const float* __restrict__ Wp = W2 + wid * 16;   // wave-uniform -> s_load
            #pragma unroll
            for (int kk = 0; kk < 16; ++kk) {
                int a4 = lane * 16 + ((kk + lane) & 15);
                f4 a = *reinterpret_cast<const f4*>(&lds[a4 * 4]);
                int k = kk * 4;
                #pragma unroll
                for (int c = 0; c < 16; ++c) {
                    acc[c] = fmaf(a.x, Wp[(k + 0) * 64 + c], acc[c]);
                    acc[c] = fmaf(a.y, Wp[(k + 1) * 64 + c], acc[c]);
                    acc[c] = fmaf(a.z, Wp[(k + 2) * 64 + c], acc[c]);
                    acc[c] = fmaf(a.w, Wp[(k + 3) * 64 + c], acc[c]);
                }
            }
        }
        __syncthreads();   // all ear reads done before m overwrites the tile
        // phase 2b: write m (row = lane, qwords wid*4..wid*4+3), same swizzle
        #pragma unroll
        for (int cc = 0; cc < 4; ++cc) {
            int qw = wid * 4 + cc;
            int a4 = lane * 16 + ((qw + lane) & 15);
            f4 w = {acc[4 * cc], acc[4 * cc + 1], acc[4 * cc + 2], acc[4 * cc + 3]};
            *reinterpret_cast<f4*>(&lds[a4 * 4]) = w;
        }
        __syncthreads();
        // phase 3: epilogue; wave wid -> edges [wid*16, wid*16+16), 4 edges/iter,
        // lane = (edge rg, column qword q): all global ops are dwordx4.
        #pragma unroll
        for (int i = 0; i < 4; ++i) {
            int r = wid * 16 + i * 4 + rg;    // tile-local edge row
            long e = e0 + r;
            int s = eidx[e];
            int d = eidx[(long)E + e];
            f4 mv = *reinterpret_cast<const f4*>(&lds[(r * 16 + ((q + r) & 15)) * 4]);
            const f4 gs = *reinterpret_cast<const f4*>(g0 + (size_t)s * 64 + q * 4);
            const f4 gd = *reinterpret_cast<const f4*>(g1 + (size_t)d * 64 + q * 4);
            mv += bgv + gs + gd;
            __builtin_nontemporal_store(mv, reinterpret_cast<f4*>(m_out + e * 64 + q * 4));
            ssum += mv;
            ssq.x = fmaf(mv.x, mv.x, ssq.x); ssq.y = fmaf(mv.y, mv.y, ssq.y);
            ssq.z = fmaf(mv.z, mv.z, ssq.z); ssq.w = fmaf(mv.w, mv.w, ssq.w);
            const f4 dl = *reinterpret_cast<const f4*>(dstL + (size_t)d * 64 + q * 4);
            float c0 = __fdividef(dl.x, 1.f + __expf(mv.x * -0.125f));
            float c1 = __fdividef(dl.y, 1.f + __expf(mv.y * -0.125f));
            float c2 = __fdividef(dl.z, 1.f + __expf(mv.z * -0.125f));
            float c3 = __fdividef(dl.w, 1.f + __expf(mv.w * -0.125f));
            float* ap = agg + (size_t)s * 64 + q * 4;
            atomic_add2(ap,     c0, c1);
            atomic_add2(ap + 2, c2, c3);
        }
        __syncthreads();   // epilogue LDS reads done before next tile's staging
    }
    // reduce stats across the 4 replicated lane-groups, then packed atomics
    #pragma unroll
    for (int m = 16; m <= 32; m <<= 1) {
        ssum.x += __shfl_xor(ssum.x, m); ssum.y += __shfl_xor(ssum.y, m);
        ssum.z += __shfl_xor(ssum.z, m); ssum.w += __shfl_xor(ssum.w, m);
        ssq.x  += __shfl_xor(ssq.x,  m); ssq.y  += __shfl_xor(ssq.y,  m);
        ssq.z  += __shfl_xor(ssq.z,  m); ssq.w  += __shfl_xor(ssq.w,  m);
    }
    if (rg == 0) {
        atomic_add2(stats + q * 4,          ssum.x, ssum.y);
        atomic_add2(stats + q * 4 + 2,      ssum.z, ssum.w);
        atomic_add2(stats + 64 + q * 4,     ssq.x,  ssq.y);
        atomic_add2(stats + 64 + q * 4 + 2, ssq.z,  ssq.w);
    }
}

__global__ void node_stats_kernel(const float* __restrict__ srcL, const float* __restrict__ agg,
                                  float* __restrict__ stats, int N)
{
    const int lane = threadIdx.x & 63;
    const int wid  = threadIdx.x >> 6;
    const int w = blockIdx.x * 4 + wid, nw = gridDim.x * 4;
    float s = 0.f, q = 0.f;
    for (int row = w; row < N; row += nw) {
        float h = srcL[(size_t)row * 64 + lane] + agg[(size_t)row * 64 + lane];
        s += h; q = fmaf(h, h, q);
    }
    atomic_add2(&stats[128 + lane & ~1], 0.f, 0.f);  // no-op keep layout simple
    (void)unsafeAtomicAdd(&stats[128 + lane], s);
    (void)unsafeAtomicAdd(&stats[192 + lane], q);
}

__global__ void finalize_kernel(float* __restrict__ stats,
                                const float* __restrict__ gn, const float* __restrict__ bn,
                                const float* __restrict__ ge, const float* __restrict__ be,
                                float invE, float invN)
{
    int c = threadIdx.x;  // 64 threads
    float mu = stats[c] * invE;
    float var = stats[64 + c] * invE - mu * mu;
    float rs = rsqrtf(var + 1e-5f);
    float sc = rs * ge[c];
    stats[256 + c] = sc;
    stats[320 + c] = be[c] - mu * sc;
    mu = stats[128 + c] * invN;
    var = stats[192 + c] * invN - mu * mu;
    rs = rsqrtf(var + 1e-5f);
    sc = rs * gn[c];
    stats[384 + c] = sc;
    stats[448 + c] = bn[c] - mu * sc;
}

__global__ void edge_norm_kernel(float* __restrict__ mbuf, const float* __restrict__ stats, long n4)
{
    long i = (long)blockIdx.x * blockDim.x + threadIdx.x;
    const long stride = (long)gridDim.x * blockDim.x;  // multiple of 16
    int c4 = (int)(i & 15) * 4;
    f4 sc = *reinterpret_cast<const f4*>(&stats[256 + c4]);
    f4 sh = *reinterpret_cast<const f4*>(&stats[320 + c4]);
    f4* p = reinterpret_cast<f4*>(mbuf);
    for (; i < n4; i += stride) {
        f4 v = __builtin_nontemporal_load(p + i);
        v.x = fmaxf(fmaf(v.x, sc.x, sh.x), 0.f);
        v.y = fmaxf(fmaf(v.y, sc.y, sh.y), 0.f);
        v.z = fmaxf(fmaf(v.z, sc.z, sh.z), 0.f);
        v.w = fmaxf(fmaf(v.w, sc.w, sh.w), 0.f);
        __builtin_nontemporal_store(v, p + i);
    }
}

__global__ void node_norm_kernel(const float* __restrict__ srcL, const float* __restrict__ agg,
                                 const float* __restrict__ stats, float* __restrict__ out, long n4)
{
    long i = (long)blockIdx.x * blockDim.x + threadIdx.x;
    const long stride = (long)gridDim.x * blockDim.x;  // multiple of 16
    int c4 = (int)(i & 15) * 4;
    f4 sc = *reinterpret_cast<const f4*>(&stats[384 + c4]);
    f4 sh = *reinterpret_cast<const f4*>(&stats[448 + c4]);
    const f4* a = reinterpret_cast<const f4*>(srcL);
    const f4* b = reinterpret_cast<const f4*>(agg);
    f4* o = reinterpret_cast<f4*>(out);
    for (; i < n4; i += stride) {
        f4 va = a[i], vb = b[i];
        f4 v = va + vb;
        v.x = fmaxf(fmaf(v.x, sc.x, sh.x), 0.f);
        v.y = fmaxf(fmaf(v.y, sc.y, sh.y), 0.f);
        v.z = fmaxf(fmaf(v.z, sc.z, sh.z), 0.f);
        v.w = fmaxf(fmaf(v.w, sc.w, sh.w), 0.f);
        o[i] = v;
    }
}

extern "C" void kernel_launch(void* const* d_in, const int* in_sizes, int n_in,
                              void* d_out, int out_size, void* d_ws, size_t ws_size,
                              hipStream_t stream)
{
    const float* x    = (const float*)d_in[0];
    const int*   eidx = (const int*)d_in[1];
    const float* ea   = (const float*)d_in[2];
    const float* Wg   = (const float*)d_in[3];
    const float* bg   = (const float*)d_in[4];
    const float* Ws   = (const float*)d_in[5];
    const float* bs   = (const float*)d_in[6];
    const float* Wd   = (const float*)d_in[7];
    const float* bd   = (const float*)d_in[8];
    const float* gn   = (const float*)d_in[9];
    const float* bn   = (const float*)d_in[10];
    const float* ge   = (const float*)d_in[11];
    const float* be   = (const float*)d_in[12];

    const int N = in_sizes[0] / 64;
    const int E = in_sizes[2] / 64;

    float* ws    = (float*)d_ws;
    size_t nb    = (size_t)N * 64;
    float* g0    = ws;
    float* g1    = ws + nb;
    float* srcL  = ws + 2 * nb;
    float* dstL  = ws + 3 * nb;
    float* agg   = ws + 4 * nb;
    float* stats = ws + 5 * nb;

    float* node_out = (float*)d_out;
    float* m_out    = node_out + nb;   // stage m in edge_out region, normalize in place

    (void)hipMemsetAsync(agg, 0, nb * sizeof(float), stream);
    (void)hipMemsetAsync(stats, 0, 512 * sizeof(float), stream);

    const int ntilesN = (N + 63) / 64;
    node_kernel<<<196, 256, 0, stream>>>(x, Wg, Ws, bs, Wd, bd, g0, g1, srcL, dstL, N, ntilesN);

    const int ntilesE = E / 64;   // E is a multiple of 64
    edge_kernel<<<2500, 256, 0, stream>>>(ea, eidx, Wg + 128 * 64, bg, g0, g1, dstL,
                                          m_out, agg, stats, E, ntilesE);

    node_stats_kernel<<<256, 256, 0, stream>>>(srcL, agg, stats, N);
    finalize_kernel<<<1, 64, 0, stream>>>(stats, gn, bn, ge, be, 1.f / (float)E, 1.f / (float)N);

    edge_norm_kernel<<<4096, 256, 0, stream>>>(m_out, stats, (long)E * 16);
    node_norm_kernel<<<1024, 256, 0, stream>>>(srcL, agg, stats, node_out, (long)N * 16);
}

// Round 6
// 2630.852 us; speedup vs baseline: 1.1371x; 1.1371x over previous
//
#include <hip/hip_runtime.h>

// GGCNConv: N=50000 nodes, E=1600000 edges (64 | E), D=64
// ws layout (floats): g0[N*64] g1[N*64] srcL[N*64] dstL[N*64] agg[N*64] stats[512]
// d_out: node_out[N*64] then edge_out[E*64]; m staged in edge_out region.

typedef float f4 __attribute__((ext_vector_type(4)));   // native vec4 for NT builtins
typedef float f2 __attribute__((ext_vector_type(2)));
typedef __attribute__((address_space(1))) f2* gf2p;     // global-AS pointer for atomics

// Native no-return packed f32 atomic add in GLOBAL address space (vmcnt-only,
// never waited on -> fire-and-forget). Flat variant would pollute lgkmcnt and
// serialize against LDS reads (R5 lesson).
__device__ __forceinline__ void atomic_add2(float* p, float a, float b) {
    f2 v = {a, b};
#if __has_builtin(__builtin_amdgcn_global_atomic_fadd_v2f32)
    (void)__builtin_amdgcn_global_atomic_fadd_v2f32((gf2p)p, v);
#elif __has_builtin(__builtin_amdgcn_flat_atomic_fadd_v2f32)
    (void)__builtin_amdgcn_flat_atomic_fadd_v2f32(reinterpret_cast<f2*>(p), v);
#else
    (void)unsafeAtomicAdd(p, a);
    (void)unsafeAtomicAdd(p + 1, b);
#endif
}

__global__ __launch_bounds__(256, 2) void node_kernel(
    const float* __restrict__ x,
    const float* __restrict__ Wg,   // Wg0 = Wg, Wg1 = Wg + 4096
    const float* __restrict__ Ws, const float* __restrict__ bs,
    const float* __restrict__ Wd, const float* __restrict__ bd,
    float* __restrict__ g0, float* __restrict__ g1,
    float* __restrict__ srcL, float* __restrict__ dstL,
    int N, int ntiles)
{
    __shared__ float ldsA[4][4096];
    const int lane = threadIdx.x & 63;
    const int wid  = threadIdx.x >> 6;
    float* lds = ldsA[wid];
    const int nw = gridDim.x * 4;
    const float bsv = bs[lane], bdv = bd[lane];

    for (int tile = blockIdx.x * 4 + wid; tile < ntiles; tile += nw) {
        const int r0 = tile * 64;
        {
            const int rb = lane >> 5, c2 = lane & 31;
            #pragma unroll
            for (int i = 0; i < 32; ++i) {
                int r = 2 * i + rb;
                int row = r0 + r; if (row >= N) row = N - 1;
                float2 v = *reinterpret_cast<const float2*>(x + (size_t)row * 64 + 2 * c2);
                int p = ((c2 + r) & 31) << 1;
                *reinterpret_cast<float2*>(&lds[r * 64 + p]) = v;
            }
        }
        float xr[64];
        #pragma unroll
        for (int kk = 0; kk < 32; ++kk) {
            int p = ((kk + lane) & 31) << 1;
            float2 v = *reinterpret_cast<const float2*>(&lds[lane * 64 + p]);
            xr[2 * kk] = v.x; xr[2 * kk + 1] = v.y;
        }
        #pragma unroll 1
        for (int mt = 0; mt < 4; ++mt) {
            const float* __restrict__ Wm = (mt == 0) ? Wg : (mt == 1) ? (Wg + 4096)
                                         : (mt == 2) ? Ws : Wd;
            #pragma unroll 1
            for (int ct = 0; ct < 2; ++ct) {
                float acc[32];
                #pragma unroll
                for (int c = 0; c < 32; ++c) acc[c] = 0.f;
                const float* __restrict__ Wp = Wm + ct * 32;
                #pragma unroll
                for (int k = 0; k < 64; ++k) {
                    float a = xr[k];
                    #pragma unroll
                    for (int c = 0; c < 32; ++c)
                        acc[c] = fmaf(a, Wp[k * 64 + c], acc[c]);
                }
                #pragma unroll
                for (int cc = 0; cc < 16; ++cc) {
                    int q = ct * 16 + cc;
                    int p = ((q + lane) & 31) << 1;
                    *reinterpret_cast<float2*>(&lds[lane * 64 + p]) =
                        make_float2(acc[2 * cc], acc[2 * cc + 1]);
                }
            }
            float bv = (mt == 2) ? bsv : (mt == 3) ? bdv : 0.f;
            float* __restrict__ op = (mt == 0) ? g0 : (mt == 1) ? g1 : (mt == 2) ? srcL : dstL;
            for (int j = 0; j < 64; ++j) {
                int row = r0 + j;
                if (row >= N) break;
                int p = ((((lane >> 1) + j) & 31) << 1) | (lane & 1);
                op[(size_t)row * 64 + lane] = lds[j * 64 + p] + bv;
            }
        }
    }
}

// Edge kernel, float4 granularity throughout.
// LDS 64x64 tile, qword-rotation swizzle: (row, q4) -> float4 slot row*16 + ((q4+row)&15)
__global__ __launch_bounds__(256, 4) void edge_kernel(
    const float* __restrict__ ea, const int* __restrict__ eidx,
    const float* __restrict__ W2, const float* __restrict__ bg,
    const float* __restrict__ g0, const float* __restrict__ g1,
    const float* __restrict__ dstL, float* __restrict__ m_out,
    float* __restrict__ agg, float* __restrict__ stats,
    int E, int ntiles)
{
    __shared__ float lds[4096];
    const int tid  = threadIdx.x;
    const int lane = tid & 63;
    const int wid  = __builtin_amdgcn_readfirstlane(tid >> 6);  // wave-uniform SGPR
    const int q    = lane & 15;   // column qword 0..15
    const int rg   = lane >> 4;   // edge-within-group 0..3
    const f4 bgv = *reinterpret_cast<const f4*>(bg + q * 4);
    f4 ssum = {0.f, 0.f, 0.f, 0.f};
    f4 ssq  = {0.f, 0.f, 0.f, 0.f};

    for (int tile = blockIdx.x; tile < ntiles; tile += gridDim.x) {
        const long e0 = (long)tile * 64;
        // phase 1: stage ea tile (1024 float4s), NT loads, swizzled b128 writes
        #pragma unroll
        for (int j = 0; j < 4; ++j) {
            int fp = tid + j * 256;           // float4 index 0..1023
            int row = fp >> 4, qc = fp & 15;  // 16 consecutive lanes -> one row
            f4 v = __builtin_nontemporal_load(
                reinterpret_cast<const f4*>(ea + (e0 + row) * 64 + qc * 4));
            int a4 = row * 16 + ((qc + row) & 15);
            *reinterpret_cast<f4*>(&lds[a4 * 4]) = v;
        }
        __syncthreads();
        // phase 2: thread owns edge row `lane`; computes cols [wid*16, wid*16+16)
        float acc[16];
        #pragma unroll
        for (int c = 0; c < 16; ++c) acc[c] = 0.f;
        {
            const float* __restrict__ Wp = W2 + wid * 16;   // wave-uniform -> s_load
            #pragma unroll
            for (int kk = 0; kk < 16; ++kk) {
                int a4 = lane * 16 + ((kk + lane) & 15);
                f4 a = *reinterpret_cast<const f4*>(&lds[a4 * 4]);
                int k = kk * 4;
                #pragma unroll
                for (int c = 0; c < 16; ++c) {
                    acc[c] = fmaf(a.x, Wp[(k + 0) * 64 + c], acc[c]);
                    acc[c] = fmaf(a.y, Wp[(k + 1) * 64 + c], acc[c]);
                    acc[c] = fmaf(a.z, Wp[(k + 2) * 64 + c], acc[c]);
                    acc[c] = fmaf(a.w, Wp[(k + 3) * 64 + c], acc[c]);
                }
            }
        }
        __syncthreads();   // all ear reads done before m overwrites the tile
        // phase 2b: write m (row = lane, qwords wid*4..wid*4+3), same swizzle
        #pragma unroll
        for (int cc = 0; cc < 4; ++cc) {
            int qw = wid * 4 + cc;
            int a4 = lane * 16 + ((qw + lane) & 15);
            f4 w = {acc[4 * cc], acc[4 * cc + 1], acc[4 * cc + 2], acc[4 * cc + 3]};
            *reinterpret_cast<f4*>(&lds[a4 * 4]) = w;
        }
        __syncthreads();
        // phase 3: epilogue; wave wid -> edges [wid*16, wid*16+16), 4 edges/iter,
        // lane = (edge rg, column qword q): all global ops are dwordx4.
        #pragma unroll
        for (int i = 0; i < 4; ++i) {
            int r = wid * 16 + i * 4 + rg;    // tile-local edge row
            long e = e0 + r;
            int s = eidx[e];
            int d = eidx[(long)E + e];
            f4 mv = *reinterpret_cast<const f4*>(&lds[(r * 16 + ((q + r) & 15)) * 4]);
            const f4 gs = *reinterpret_cast<const f4*>(g0 + (size_t)s * 64 + q * 4);
            const f4 gd = *reinterpret_cast<const f4*>(g1 + (size_t)d * 64 + q * 4);
            mv += bgv + gs + gd;
            *reinterpret_cast<f4*>(m_out + e * 64 + q * 4) = mv;   // normal store (no NT!)
            ssum += mv;
            ssq.x = fmaf(mv.x, mv.x, ssq.x); ssq.y = fmaf(mv.y, mv.y, ssq.y);
            ssq.z = fmaf(mv.z, mv.z, ssq.z); ssq.w = fmaf(mv.w, mv.w, ssq.w);
            const f4 dl = *reinterpret_cast<const f4*>(dstL + (size_t)d * 64 + q * 4);
            float c0 = __fdividef(dl.x, 1.f + __expf(mv.x * -0.125f));
            float c1 = __fdividef(dl.y, 1.f + __expf(mv.y * -0.125f));
            float c2 = __fdividef(dl.z, 1.f + __expf(mv.z * -0.125f));
            float c3 = __fdividef(dl.w, 1.f + __expf(mv.w * -0.125f));
            float* ap = agg + (size_t)s * 64 + q * 4;
            atomic_add2(ap,     c0, c1);
            atomic_add2(ap + 2, c2, c3);
        }
        __syncthreads();   // epilogue LDS reads done before next tile's staging
    }
    // reduce stats across the 4 replicated lane-groups, then packed atomics
    #pragma unroll
    for (int m = 16; m <= 32; m <<= 1) {
        ssum.x += __shfl_xor(ssum.x, m); ssum.y += __shfl_xor(ssum.y, m);
        ssum.z += __shfl_xor(ssum.z, m); ssum.w += __shfl_xor(ssum.w, m);
        ssq.x  += __shfl_xor(ssq.x,  m); ssq.y  += __shfl_xor(ssq.y,  m);
        ssq.z  += __shfl_xor(ssq.z,  m); ssq.w  += __shfl_xor(ssq.w,  m);
    }
    if (rg == 0) {
        atomic_add2(stats + q * 4,          ssum.x, ssum.y);
        atomic_add2(stats + q * 4 + 2,      ssum.z, ssum.w);
        atomic_add2(stats + 64 + q * 4,     ssq.x,  ssq.y);
        atomic_add2(stats + 64 + q * 4 + 2, ssq.z,  ssq.w);
    }
}

__global__ void node_stats_kernel(const float* __restrict__ srcL, const float* __restrict__ agg,
                                  float* __restrict__ stats, int N)
{
    const int lane = threadIdx.x & 63;
    const int wid  = threadIdx.x >> 6;
    const int w = blockIdx.x * 4 + wid, nw = gridDim.x * 4;
    float s = 0.f, q = 0.f;
    for (int row = w; row < N; row += nw) {
        float h = srcL[(size_t)row * 64 + lane] + agg[(size_t)row * 64 + lane];
        s += h; q = fmaf(h, h, q);
    }
    (void)unsafeAtomicAdd(&stats[128 + lane], s);
    (void)unsafeAtomicAdd(&stats[192 + lane], q);
}

__global__ void finalize_kernel(float* __restrict__ stats,
                                const float* __restrict__ gn, const float* __restrict__ bn,
                                const float* __restrict__ ge, const float* __restrict__ be,
                                float invE, float invN)
{
    int c = threadIdx.x;  // 64 threads
    float mu = stats[c] * invE;
    float var = stats[64 + c] * invE - mu * mu;
    float rs = rsqrtf(var + 1e-5f);
    float sc = rs * ge[c];
    stats[256 + c] = sc;
    stats[320 + c] = be[c] - mu * sc;
    mu = stats[128 + c] * invN;
    var = stats[192 + c] * invN - mu * mu;
    rs = rsqrtf(var + 1e-5f);
    sc = rs * gn[c];
    stats[384 + c] = sc;
    stats[448 + c] = bn[c] - mu * sc;
}

__global__ void edge_norm_kernel(float* __restrict__ mbuf, const float* __restrict__ stats, long n4)
{
    long i = (long)blockIdx.x * blockDim.x + threadIdx.x;
    const long stride = (long)gridDim.x * blockDim.x;  // multiple of 16
    int c4 = (int)(i & 15) * 4;
    f4 sc = *reinterpret_cast<const f4*>(&stats[256 + c4]);
    f4 sh = *reinterpret_cast<const f4*>(&stats[320 + c4]);
    f4* p = reinterpret_cast<f4*>(mbuf);
    for (; i < n4; i += stride) {
        f4 v = p[i];
        v.x = fmaxf(fmaf(v.x, sc.x, sh.x), 0.f);
        v.y = fmaxf(fmaf(v.y, sc.y, sh.y), 0.f);
        v.z = fmaxf(fmaf(v.z, sc.z, sh.z), 0.f);
        v.w = fmaxf(fmaf(v.w, sc.w, sh.w), 0.f);
        p[i] = v;
    }
}

__global__ void node_norm_kernel(const float* __restrict__ srcL, const float* __restrict__ agg,
                                 const float* __restrict__ stats, float* __restrict__ out, long n4)
{
    long i = (long)blockIdx.x * blockDim.x + threadIdx.x;
    const long stride = (long)gridDim.x * blockDim.x;  // multiple of 16
    int c4 = (int)(i & 15) * 4;
    f4 sc = *reinterpret_cast<const f4*>(&stats[384 + c4]);
    f4 sh = *reinterpret_cast<const f4*>(&stats[448 + c4]);
    const f4* a = reinterpret_cast<const f4*>(srcL);
    const f4* b = reinterpret_cast<const f4*>(agg);
    f4* o = reinterpret_cast<f4*>(out);
    for (; i < n4; i += stride) {
        f4 va = a[i], vb = b[i];
        f4 v = va + vb;
        v.x = fmaxf(fmaf(v.x, sc.x, sh.x), 0.f);
        v.y = fmaxf(fmaf(v.y, sc.y, sh.y), 0.f);
        v.z = fmaxf(fmaf(v.z, sc.z, sh.z), 0.f);
        v.w = fmaxf(fmaf(v.w, sc.w, sh.w), 0.f);
        o[i] = v;
    }
}

extern "C" void kernel_launch(void* const* d_in, const int* in_sizes, int n_in,
                              void* d_out, int out_size, void* d_ws, size_t ws_size,
                              hipStream_t stream)
{
    const float* x    = (const float*)d_in[0];
    const int*   eidx = (const int*)d_in[1];
    const float* ea   = (const float*)d_in[2];
    const float* Wg   = (const float*)d_in[3];
    const float* bg   = (const float*)d_in[4];
    const float* Ws   = (const float*)d_in[5];
    const float* bs   = (const float*)d_in[6];
    const float* Wd   = (const float*)d_in[7];
    const float* bd   = (const float*)d_in[8];
    const float* gn   = (const float*)d_in[9];
    const float* bn   = (const float*)d_in[10];
    const float* ge   = (const float*)d_in[11];
    const float* be   = (const float*)d_in[12];

    const int N = in_sizes[0] / 64;
    const int E = in_sizes[2] / 64;

    float* ws    = (float*)d_ws;
    size_t nb    = (size_t)N * 64;
    float* g0    = ws;
    float* g1    = ws + nb;
    float* srcL  = ws + 2 * nb;
    float* dstL  = ws + 3 * nb;
    float* agg   = ws + 4 * nb;
    float* stats = ws + 5 * nb;

    float* node_out = (float*)d_out;
    float* m_out    = node_out + nb;   // stage m in edge_out region, normalize in place

    (void)hipMemsetAsync(agg, 0, nb * sizeof(float), stream);
    (void)hipMemsetAsync(stats, 0, 512 * sizeof(float), stream);

    const int ntilesN = (N + 63) / 64;
    node_kernel<<<196, 256, 0, stream>>>(x, Wg, Ws, bs, Wd, bd, g0, g1, srcL, dstL, N, ntilesN);

    const int ntilesE = E / 64;   // E is a multiple of 64
    edge_kernel<<<2500, 256, 0, stream>>>(ea, eidx, Wg + 128 * 64, bg, g0, g1, dstL,
                                          m_out, agg, stats, E, ntilesE);

    node_stats_kernel<<<256, 256, 0, stream>>>(srcL, agg, stats, N);
    finalize_kernel<<<1, 64, 0, stream>>>(stats, gn, bn, ge, be, 1.f / (float)E, 1.f / (float)N);

    edge_norm_kernel<<<4096, 256, 0, stream>>>(m_out, stats, (long)E * 16);
    node_norm_kernel<<<1024, 256, 0, stream>>>(srcL, agg, stats, node_out, (long)N * 16);
}

// Round 7
// 2163.955 us; speedup vs baseline: 1.3824x; 1.2158x over previous
//
#include <hip/hip_runtime.h>

// GGCNConv: N=50000 nodes, E=1600000 edges (64 | E), D=64
// CSR two-phase: no float atomics anywhere on the hot path.
// ws (floats): g0[nb] g1[nb] srcL[nb] dstL[nb] stats[512] | ints: cnt[N] base[N+1] sorted[E]
//   h[nb] aliases g0 (g0 dead after edge_kernel; h written by agg_kernel afterwards).
// d_out: node_out[N*64] then edge_out[E*64]; m staged in edge_out region.

typedef float f4 __attribute__((ext_vector_type(4)));

__global__ __launch_bounds__(256, 2) void node_kernel(
    const float* __restrict__ x,
    const float* __restrict__ Wg,   // Wg0 = Wg, Wg1 = Wg + 4096
    const float* __restrict__ Ws, const float* __restrict__ bs,
    const float* __restrict__ Wd, const float* __restrict__ bd,
    float* __restrict__ g0, float* __restrict__ g1,
    float* __restrict__ srcL, float* __restrict__ dstL,
    int N, int ntiles)
{
    __shared__ float ldsA[4][4096];
    const int lane = threadIdx.x & 63;
    const int wid  = threadIdx.x >> 6;
    float* lds = ldsA[wid];
    const int nw = gridDim.x * 4;
    const float bsv = bs[lane], bdv = bd[lane];

    for (int tile = blockIdx.x * 4 + wid; tile < ntiles; tile += nw) {
        const int r0 = tile * 64;
        {
            const int rb = lane >> 5, c2 = lane & 31;
            #pragma unroll
            for (int i = 0; i < 32; ++i) {
                int r = 2 * i + rb;
                int row = r0 + r; if (row >= N) row = N - 1;
                float2 v = *reinterpret_cast<const float2*>(x + (size_t)row * 64 + 2 * c2);
                int p = ((c2 + r) & 31) << 1;
                *reinterpret_cast<float2*>(&lds[r * 64 + p]) = v;
            }
        }
        float xr[64];
        #pragma unroll
        for (int kk = 0; kk < 32; ++kk) {
            int p = ((kk + lane) & 31) << 1;
            float2 v = *reinterpret_cast<const float2*>(&lds[lane * 64 + p]);
            xr[2 * kk] = v.x; xr[2 * kk + 1] = v.y;
        }
        #pragma unroll 1
        for (int mt = 0; mt < 4; ++mt) {
            const float* __restrict__ Wm = (mt == 0) ? Wg : (mt == 1) ? (Wg + 4096)
                                         : (mt == 2) ? Ws : Wd;
            #pragma unroll 1
            for (int ct = 0; ct < 2; ++ct) {
                float acc[32];
                #pragma unroll
                for (int c = 0; c < 32; ++c) acc[c] = 0.f;
                const float* __restrict__ Wp = Wm + ct * 32;
                #pragma unroll
                for (int k = 0; k < 64; ++k) {
                    float a = xr[k];
                    #pragma unroll
                    for (int c = 0; c < 32; ++c)
                        acc[c] = fmaf(a, Wp[k * 64 + c], acc[c]);
                }
                #pragma unroll
                for (int cc = 0; cc < 16; ++cc) {
                    int q = ct * 16 + cc;
                    int p = ((q + lane) & 31) << 1;
                    *reinterpret_cast<float2*>(&lds[lane * 64 + p]) =
                        make_float2(acc[2 * cc], acc[2 * cc + 1]);
                }
            }
            float bv = (mt == 2) ? bsv : (mt == 3) ? bdv : 0.f;
            float* __restrict__ op = (mt == 0) ? g0 : (mt == 1) ? g1 : (mt == 2) ? srcL : dstL;
            for (int j = 0; j < 64; ++j) {
                int row = r0 + j;
                if (row >= N) break;
                int p = ((((lane >> 1) + j) & 31) << 1) | (lane & 1);
                op[(size_t)row * 64 + lane] = lds[j * 64 + p] + bv;
            }
        }
    }
}

// ---------- CSR build ----------
__global__ void hist_kernel(const int* __restrict__ esrc, int* __restrict__ cnt, int E)
{
    int i = blockIdx.x * blockDim.x + threadIdx.x;
    const int stride = gridDim.x * blockDim.x;
    for (; i < E; i += stride) atomicAdd(&cnt[esrc[i]], 1);
}

__global__ __launch_bounds__(1024) void scan_kernel(int* __restrict__ cnt, int* __restrict__ base, int N)
{
    __shared__ int bufA[1024], bufB[1024];
    const int t = threadIdx.x;
    const int chunk = (N + 1023) >> 10;
    const int lo = t * chunk;
    const int hi = (lo + chunk < N) ? lo + chunk : N;
    int s = 0;
    for (int i = lo; i < hi; ++i) s += cnt[i];
    int* a = bufA; int* b = bufB;
    a[t] = s;
    __syncthreads();
    for (int off = 1; off < 1024; off <<= 1) {
        int v = a[t] + ((t >= off) ? a[t - off] : 0);
        __syncthreads();
        b[t] = v;
        __syncthreads();
        int* tmp = a; a = b; b = tmp;
    }
    int run = a[t] - s;   // exclusive prefix of this thread's chunk
    for (int i = lo; i < hi; ++i) {
        int c = cnt[i];
        base[i] = run;
        cnt[i]  = run;    // cursor for scatter
        run += c;
    }
    if (t == 1023) base[N] = a[1023];
}

__global__ void scatter_kernel(const int* __restrict__ esrc, int* __restrict__ cursor,
                               int* __restrict__ sorted, int E)
{
    int i = blockIdx.x * blockDim.x + threadIdx.x;
    const int stride = gridDim.x * blockDim.x;
    for (; i < E; i += stride) {
        int pos = atomicAdd(&cursor[esrc[i]], 1);
        sorted[pos] = i;
    }
}

// ---------- Edge kernel: m = ea@W2 + bg + g0[src] + g1[dst]; edge stats ----------
__global__ __launch_bounds__(256, 4) void edge_kernel(
    const float* __restrict__ ea, const int* __restrict__ eidx,
    const float* __restrict__ W2, const float* __restrict__ bg,
    const float* __restrict__ g0, const float* __restrict__ g1,
    float* __restrict__ m_out, float* __restrict__ stats,
    int E, int ntiles)
{
    __shared__ float lds[4096];
    const int tid  = threadIdx.x;
    const int lane = tid & 63;
    const int wid  = __builtin_amdgcn_readfirstlane(tid >> 6);
    const int q    = lane & 15;   // column qword 0..15
    const int rg   = lane >> 4;   // edge-within-group 0..3
    const f4 bgv = *reinterpret_cast<const f4*>(bg + q * 4);
    f4 ssum = {0.f, 0.f, 0.f, 0.f};
    f4 ssq  = {0.f, 0.f, 0.f, 0.f};

    for (int tile = blockIdx.x; tile < ntiles; tile += gridDim.x) {
        const long e0 = (long)tile * 64;
        #pragma unroll
        for (int j = 0; j < 4; ++j) {
            int fp = tid + j * 256;
            int row = fp >> 4, qc = fp & 15;
            f4 v = __builtin_nontemporal_load(
                reinterpret_cast<const f4*>(ea + (e0 + row) * 64 + qc * 4));
            int a4 = row * 16 + ((qc + row) & 15);
            *reinterpret_cast<f4*>(&lds[a4 * 4]) = v;
        }
        __syncthreads();
        float acc[16];
        #pragma unroll
        for (int c = 0; c < 16; ++c) acc[c] = 0.f;
        {
            const float* __restrict__ Wp = W2 + wid * 16;   // wave-uniform -> s_load
            #pragma unroll
            for (int kk = 0; kk < 16; ++kk) {
                int a4 = lane * 16 + ((kk + lane) & 15);
                f4 a = *reinterpret_cast<const f4*>(&lds[a4 * 4]);
                int k = kk * 4;
                #pragma unroll
                for (int c = 0; c < 16; ++c) {
                    acc[c] = fmaf(a.x, Wp[(k + 0) * 64 + c], acc[c]);
                    acc[c] = fmaf(a.y, Wp[(k + 1) * 64 + c], acc[c]);
                    acc[c] = fmaf(a.z, Wp[(k + 2) * 64 + c], acc[c]);
                    acc[c] = fmaf(a.w, Wp[(k + 3) * 64 + c], acc[c]);
                }
            }
        }
        __syncthreads();
        #pragma unroll
        for (int cc = 0; cc < 4; ++cc) {
            int qw = wid * 4 + cc;
            int a4 = lane * 16 + ((qw + lane) & 15);
            f4 w = {acc[4 * cc], acc[4 * cc + 1], acc[4 * cc + 2], acc[4 * cc + 3]};
            *reinterpret_cast<f4*>(&lds[a4 * 4]) = w;
        }
        __syncthreads();
        #pragma unroll
        for (int i = 0; i < 4; ++i) {
            int r = wid * 16 + i * 4 + rg;
            long e = e0 + r;
            int s = eidx[e];
            int d = eidx[(long)E + e];
            f4 mv = *reinterpret_cast<const f4*>(&lds[(r * 16 + ((q + r) & 15)) * 4]);
            const f4 gs = *reinterpret_cast<const f4*>(g0 + (size_t)s * 64 + q * 4);
            const f4 gd = *reinterpret_cast<const f4*>(g1 + (size_t)d * 64 + q * 4);
            mv += bgv + gs + gd;
            *reinterpret_cast<f4*>(m_out + e * 64 + q * 4) = mv;
            ssum += mv;
            ssq.x = fmaf(mv.x, mv.x, ssq.x); ssq.y = fmaf(mv.y, mv.y, ssq.y);
            ssq.z = fmaf(mv.z, mv.z, ssq.z); ssq.w = fmaf(mv.w, mv.w, ssq.w);
        }
        __syncthreads();
    }
    #pragma unroll
    for (int m = 16; m <= 32; m <<= 1) {
        ssum.x += __shfl_xor(ssum.x, m); ssum.y += __shfl_xor(ssum.y, m);
        ssum.z += __shfl_xor(ssum.z, m); ssum.w += __shfl_xor(ssum.w, m);
        ssq.x  += __shfl_xor(ssq.x,  m); ssq.y  += __shfl_xor(ssq.y,  m);
        ssq.z  += __shfl_xor(ssq.z,  m); ssq.w  += __shfl_xor(ssq.w,  m);
    }
    if (rg == 0) {
        (void)unsafeAtomicAdd(stats + q * 4 + 0, ssum.x);
        (void)unsafeAtomicAdd(stats + q * 4 + 1, ssum.y);
        (void)unsafeAtomicAdd(stats + q * 4 + 2, ssum.z);
        (void)unsafeAtomicAdd(stats + q * 4 + 3, ssum.w);
        (void)unsafeAtomicAdd(stats + 64 + q * 4 + 0, ssq.x);
        (void)unsafeAtomicAdd(stats + 64 + q * 4 + 1, ssq.y);
        (void)unsafeAtomicAdd(stats + 64 + q * 4 + 2, ssq.z);
        (void)unsafeAtomicAdd(stats + 64 + q * 4 + 3, ssq.w);
    }
}

// ---------- Aggregation: wave per node, register accumulate, no atomics ----------
__global__ __launch_bounds__(256, 4) void agg_kernel(
    const float* __restrict__ srcL, const float* __restrict__ dstL,
    const float* __restrict__ m, const int* __restrict__ edst,
    const int* __restrict__ base, const int* __restrict__ sorted,
    float* __restrict__ h, float* __restrict__ stats, int N)
{
    const int lane = threadIdx.x & 63;
    const int wv = (blockIdx.x * blockDim.x + threadIdx.x) >> 6;
    const int nw = (gridDim.x * blockDim.x) >> 6;
    float ls = 0.f, lq = 0.f;
    for (int n = wv; n < N; n += nw) {
        const int b0 = base[n], b1 = base[n + 1];
        float acc = srcL[(size_t)n * 64 + lane];
        int k = b0;
        if (k < b1) {
            int e = __builtin_amdgcn_readfirstlane(sorted[k]);
            int d = __builtin_amdgcn_readfirstlane(edst[e]);
            for (; k + 1 < b1; ++k) {
                int e1 = sorted[k + 1];                 // issue next-index loads early
                float mv = m[(size_t)e * 64 + lane];
                float dl = dstL[(size_t)d * 64 + lane];
                e1 = __builtin_amdgcn_readfirstlane(e1);
                int d1 = __builtin_amdgcn_readfirstlane(edst[e1]);
                acc = fmaf(dl, __fdividef(1.f, 1.f + __expf(mv * -0.125f)), acc);
                e = e1; d = d1;
            }
            float mv = m[(size_t)e * 64 + lane];
            float dl = dstL[(size_t)d * 64 + lane];
            acc = fmaf(dl, __fdividef(1.f, 1.f + __expf(mv * -0.125f)), acc);
        }
        h[(size_t)n * 64 + lane] = acc;
        ls += acc; lq = fmaf(acc, acc, lq);
    }
    (void)unsafeAtomicAdd(&stats[128 + lane], ls);
    (void)unsafeAtomicAdd(&stats[192 + lane], lq);
}

__global__ void finalize_kernel(float* __restrict__ stats,
                                const float* __restrict__ gn, const float* __restrict__ bn,
                                const float* __restrict__ ge, const float* __restrict__ be,
                                float invE, float invN)
{
    int c = threadIdx.x;  // 64 threads
    float mu = stats[c] * invE;
    float var = stats[64 + c] * invE - mu * mu;
    float rs = rsqrtf(var + 1e-5f);
    float sc = rs * ge[c];
    stats[256 + c] = sc;
    stats[320 + c] = be[c] - mu * sc;
    mu = stats[128 + c] * invN;
    var = stats[192 + c] * invN - mu * mu;
    rs = rsqrtf(var + 1e-5f);
    sc = rs * gn[c];
    stats[384 + c] = sc;
    stats[448 + c] = bn[c] - mu * sc;
}

__global__ void edge_norm_kernel(float* __restrict__ mbuf, const float* __restrict__ stats, long n4)
{
    long i = (long)blockIdx.x * blockDim.x + threadIdx.x;
    const long stride = (long)gridDim.x * blockDim.x;  // multiple of 16
    int c4 = (int)(i & 15) * 4;
    f4 sc = *reinterpret_cast<const f4*>(&stats[256 + c4]);
    f4 sh = *reinterpret_cast<const f4*>(&stats[320 + c4]);
    f4* p = reinterpret_cast<f4*>(mbuf);
    for (; i < n4; i += stride) {
        f4 v = p[i];
        v.x = fmaxf(fmaf(v.x, sc.x, sh.x), 0.f);
        v.y = fmaxf(fmaf(v.y, sc.y, sh.y), 0.f);
        v.z = fmaxf(fmaf(v.z, sc.z, sh.z), 0.f);
        v.w = fmaxf(fmaf(v.w, sc.w, sh.w), 0.f);
        p[i] = v;
    }
}

__global__ void node_norm_kernel(const float* __restrict__ h, const float* __restrict__ stats,
                                 float* __restrict__ out, long n4)
{
    long i = (long)blockIdx.x * blockDim.x + threadIdx.x;
    const long stride = (long)gridDim.x * blockDim.x;  // multiple of 16
    int c4 = (int)(i & 15) * 4;
    f4 sc = *reinterpret_cast<const f4*>(&stats[384 + c4]);
    f4 sh = *reinterpret_cast<const f4*>(&stats[448 + c4]);
    const f4* a = reinterpret_cast<const f4*>(h);
    f4* o = reinterpret_cast<f4*>(out);
    for (; i < n4; i += stride) {
        f4 v = a[i];
        v.x = fmaxf(fmaf(v.x, sc.x, sh.x), 0.f);
        v.y = fmaxf(fmaf(v.y, sc.y, sh.y), 0.f);
        v.z = fmaxf(fmaf(v.z, sc.z, sh.z), 0.f);
        v.w = fmaxf(fmaf(v.w, sc.w, sh.w), 0.f);
        o[i] = v;
    }
}

extern "C" void kernel_launch(void* const* d_in, const int* in_sizes, int n_in,
                              void* d_out, int out_size, void* d_ws, size_t ws_size,
                              hipStream_t stream)
{
    const float* x    = (const float*)d_in[0];
    const int*   eidx = (const int*)d_in[1];
    const float* ea   = (const float*)d_in[2];
    const float* Wg   = (const float*)d_in[3];
    const float* bg   = (const float*)d_in[4];
    const float* Ws   = (const float*)d_in[5];
    const float* bs   = (const float*)d_in[6];
    const float* Wd   = (const float*)d_in[7];
    const float* bd   = (const float*)d_in[8];
    const float* gn   = (const float*)d_in[9];
    const float* bn   = (const float*)d_in[10];
    const float* ge   = (const float*)d_in[11];
    const float* be   = (const float*)d_in[12];

    const int N = in_sizes[0] / 64;
    const int E = in_sizes[2] / 64;

    float* ws    = (float*)d_ws;
    size_t nb    = (size_t)N * 64;
    float* g0    = ws;                 // h aliases g0 after edge_kernel
    float* g1    = ws + nb;
    float* srcL  = ws + 2 * nb;
    float* dstL  = ws + 3 * nb;
    float* stats = ws + 4 * nb;
    int*   cnt    = (int*)(stats + 512);
    int*   base   = cnt + N;
    int*   sorted = base + N + 1;
    float* h      = g0;

    float* node_out = (float*)d_out;
    float* m_out    = node_out + nb;   // stage m in edge_out region, normalize in place

    (void)hipMemsetAsync(cnt, 0, (size_t)N * sizeof(int), stream);
    (void)hipMemsetAsync(stats, 0, 512 * sizeof(float), stream);

    // CSR build (independent of node/edge compute)
    hist_kernel<<<2048, 256, 0, stream>>>(eidx, cnt, E);
    scan_kernel<<<1, 1024, 0, stream>>>(cnt, base, N);
    scatter_kernel<<<2048, 256, 0, stream>>>(eidx, cnt, sorted, E);

    const int ntilesN = (N + 63) / 64;
    node_kernel<<<196, 256, 0, stream>>>(x, Wg, Ws, bs, Wd, bd, g0, g1, srcL, dstL, N, ntilesN);

    const int ntilesE = E / 64;
    edge_kernel<<<2500, 256, 0, stream>>>(ea, eidx, Wg + 128 * 64, bg, g0, g1,
                                          m_out, stats, E, ntilesE);

    agg_kernel<<<2500, 256, 0, stream>>>(srcL, dstL, m_out, eidx + E, base, sorted,
                                         h, stats, N);

    finalize_kernel<<<1, 64, 0, stream>>>(stats, gn, bn, ge, be, 1.f / (float)E, 1.f / (float)N);

    edge_norm_kernel<<<4096, 256, 0, stream>>>(m_out, stats, (long)E * 16);
    node_norm_kernel<<<1024, 256, 0, stream>>>(h, stats, node_out, (long)N * 16);
}